// Round 7
// baseline (364.940 us; speedup 1.0000x reference)
//
#include <hip/hip_runtime.h>
#include <hip/hip_bf16.h>
#include <hip/hip_fp16.h>

#define N_NODES 50000
#define E_EDGES 1600000
#define EP (E_EDGES + N_NODES)   // edges + self loops = 1650000
#define IN_CH 128
#define HID 32
#define HEADS 4
#define HC (HEADS * HID)         // 128
#define OUT_CH 16
#define B_GRAPHS 512
#define NEG_SLOPE 0.2f
#define CAP 96                   // bucket capacity; deg = 1+Pois(32), P(>96)~1e-18

__device__ __forceinline__ unsigned short f2bf(float f) {
    unsigned int u = __float_as_uint(f);
    unsigned int r = (u + 0x7FFFu + ((u >> 16) & 1u)) >> 16;   // RNE
    return (unsigned short)r;
}

// ---- K1: pure GEMM h = x@W1 (8x4 reg tile, k-vec4) + bf16 h + attn ------
#define ROWS_PB 64
__global__ __launch_bounds__(256) void k_gemm_h(const float* __restrict__ x,
                                                const float* __restrict__ W1,
                                                const float* __restrict__ att_src,
                                                const float* __restrict__ att_dst,
                                                unsigned short* __restrict__ hb,
                                                float* __restrict__ a_s,
                                                float* __restrict__ a_d) {
    __shared__ float smem[12288];          // 48 KB: sX 8192 | sW 4096
    float* sX = smem;                      // [64][128]
    float* sW = smem + 8192;               // [32][128]
    const int t = threadIdx.x;
    const int n0 = blockIdx.x * ROWS_PB;

    // stage x tile (float4)
    for (int i = t; i < ROWS_PB * 32; i += 256) {
        int r = i >> 5, c4 = i & 31;
        int n = n0 + r;
        float4 v = (n < N_NODES) ? ((const float4*)x)[(size_t)n * 32 + c4]
                                 : make_float4(0.f, 0.f, 0.f, 0.f);
        ((float4*)sX)[i] = v;
    }

    float acc[8][4];
#pragma unroll
    for (int j = 0; j < 8; j++)
#pragma unroll
        for (int c = 0; c < 4; c++) acc[j][c] = 0.f;

    const int tx = t & 31;    // col group: cols 4tx..4tx+3
    const int ty = t >> 5;    // row group: rows 8ty..8ty+7

    for (int kb = 0; kb < 4; kb++) {
        __syncthreads();
        for (int i = t; i < 32 * 32; i += 256) {
            ((float4*)sW)[i] =
                ((const float4*)W1)[(size_t)(kb * 32 + (i >> 5)) * 32 + (i & 31)];
        }
        __syncthreads();
#pragma unroll
        for (int kk = 0; kk < 32; kk += 4) {
            float4 w0 = *(float4*)&sW[(kk + 0) * 128 + tx * 4];
            float4 w1 = *(float4*)&sW[(kk + 1) * 128 + tx * 4];
            float4 w2 = *(float4*)&sW[(kk + 2) * 128 + tx * 4];
            float4 w3 = *(float4*)&sW[(kk + 3) * 128 + tx * 4];
#pragma unroll
            for (int j = 0; j < 8; j++) {
                float4 xv = *(float4*)&sX[(ty * 8 + j) * 128 + kb * 32 + kk];
                acc[j][0] += xv.x * w0.x + xv.y * w1.x + xv.z * w2.x + xv.w * w3.x;
                acc[j][1] += xv.x * w0.y + xv.y * w1.y + xv.z * w2.y + xv.w * w3.y;
                acc[j][2] += xv.x * w0.z + xv.y * w1.z + xv.z * w2.z + xv.w * w3.z;
                acc[j][3] += xv.x * w0.w + xv.y * w1.w + xv.z * w2.w + xv.w * w3.w;
            }
        }
    }

    // store h as bf16 (ushort4 = 4 channels)
#pragma unroll
    for (int j = 0; j < 8; j++) {
        int n = n0 + ty * 8 + j;
        if (n < N_NODES) {
            ushort4 o;
            o.x = f2bf(acc[j][0]); o.y = f2bf(acc[j][1]);
            o.z = f2bf(acc[j][2]); o.w = f2bf(acc[j][3]);
            *(ushort4*)&hb[(size_t)n * HC + tx * 4] = o;
        }
    }

    // attention scores from the fp32 tile (restash with pad-129)
    __syncthreads();
    float* sH = smem;                      // [64][129] = 33 KB
#pragma unroll
    for (int j = 0; j < 8; j++) {
        float* row = &sH[(ty * 8 + j) * 129 + tx * 4];
        row[0] = acc[j][0]; row[1] = acc[j][1];
        row[2] = acc[j][2]; row[3] = acc[j][3];
    }
    __syncthreads();
    if (t < 128) {
        int r = t & 63;
        int n = n0 + r;
        const float* __restrict__ av = (t < 64) ? att_src : att_dst;
        float s0 = 0.f, s1 = 0.f, s2 = 0.f, s3 = 0.f;
#pragma unroll 4
        for (int j = 0; j < 32; j++) {
            const float* row = &sH[r * 129 + j];
            s0 += row[0]  * av[j];
            s1 += row[32] * av[32 + j];
            s2 += row[64] * av[64 + j];
            s3 += row[96] * av[96 + j];
        }
        if (n < N_NODES) {
            float* dst = (t < 64) ? a_s : a_d;
            *(float4*)(dst + (size_t)n * 4) = make_float4(s0, s1, s2, s3);
        }
    }
}

// ---- K2: bucket fill, one thread per edge (max TLP) ---------------------
__global__ __launch_bounds__(256) void k_bucket(const int* __restrict__ ei,
                                                int* __restrict__ cnt,
                                                int* __restrict__ csr_src) {
    int e = blockIdx.x * 256 + threadIdx.x;
    if (e >= EP) return;
    int s, d;
    if (e < E_EDGES) { s = ei[e]; d = ei[E_EDGES + e]; }
    else             { s = d = e - E_EDGES; }
    int c = atomicAdd(&cnt[d], 1);
    if (c < CAP) csr_src[(size_t)d * CAP + c] = s;
}

// ---- K3: slot-parallel edge-weight compute in bucket order --------------
__device__ __forceinline__ float lrelu_exp(float v) {
    v = v > 0.f ? v : NEG_SLOPE * v;
    return __expf(v);
}

__global__ __launch_bounds__(256) void k_ev(const int* __restrict__ csr_src,
                                            const int* __restrict__ cnt,
                                            const float* __restrict__ a_s,
                                            const float* __restrict__ a_d,
                                            uint2* __restrict__ csr_ev) {
    int slot = blockIdx.x * 256 + threadIdx.x;          // < N_NODES*CAP = 4.8M
    int row = slot / CAP;                               // magic-mul division
    int idx = slot - row * CAP;
    int c = cnt[row]; if (c > CAP) c = CAP;
    if (idx >= c) return;
    int s = csr_src[slot];
    float4 as = *(const float4*)(a_s + (size_t)s * 4);
    float4 ad = *(const float4*)(a_d + (size_t)row * 4);
    __half2 h01 = __floats2half2_rn(lrelu_exp(as.x + ad.x), lrelu_exp(as.y + ad.y));
    __half2 h23 = __floats2half2_rn(lrelu_exp(as.z + ad.z), lrelu_exp(as.w + ad.w));
    uint2 rec;
    rec.x = *(unsigned int*)&h01;
    rec.y = *(unsigned int*)&h23;
    csr_ev[slot] = rec;
}

// ---- K4: channel-per-thread bucket aggregate (bf16 h, fp16 ev) + pool ---
#define AGG_CHUNK 8
__global__ __launch_bounds__(128) void k_agg_pool(const int* __restrict__ cnt,
                                                  const int* __restrict__ csr_src,
                                                  const uint2* __restrict__ csr_ev,
                                                  const unsigned short* __restrict__ hb,
                                                  const float* __restrict__ b1,
                                                  const int* __restrict__ batch,
                                                  float* __restrict__ g) {
    const int f = threadIdx.x;       // 0..127 feature channel
    const int head = f >> 5;         // 0..3
    const int n0 = blockIdx.x * AGG_CHUNK;
    const float bias = b1[f];
    float pool = 0.f;
    int cur = batch[n0];
    for (int n = n0; n < n0 + AGG_CHUNK; n++) {
        int b = batch[n];
        if (b != cur) {                        // uniform branch
            atomicAdd(&g[(size_t)cur * HC + f], pool);
            pool = 0.f;
            cur = b;
        }
        int c = cnt[n]; if (c > CAP) c = CAP;
        const int rs = n * CAP;
        const int re = rs + c;
        float acc = 0.f, dsum = 0.f;
        int i = rs;
#pragma unroll 2
        for (; i + 2 <= re; i += 2) {          // 2-edge interleave for MLP
            int s0 = csr_src[i];
            int s1 = csr_src[i + 1];
            const __half* e0 = (const __half*)(csr_ev + i);
            const __half* e1 = (const __half*)(csr_ev + i + 1);
            float w0 = __half2float(e0[head]);
            float w1 = __half2float(e1[head]);
            unsigned short u0 = hb[(size_t)s0 * HC + f];   // coalesced 256B
            unsigned short u1 = hb[(size_t)s1 * HC + f];
            dsum += w0 + w1;
            acc += w0 * __uint_as_float((unsigned int)u0 << 16)
                 + w1 * __uint_as_float((unsigned int)u1 << 16);
        }
        if (i < re) {
            int s0 = csr_src[i];
            float w0 = __half2float(((const __half*)(csr_ev + i))[head]);
            unsigned short u0 = hb[(size_t)s0 * HC + f];
            dsum += w0;
            acc += w0 * __uint_as_float((unsigned int)u0 << 16);
        }
        float inv = 1.f / (dsum + 1e-16f);
        float val = acc * inv + bias;
        val = val > 0.f ? val : (__expf(val) - 1.f);       // ELU
        pool += val;
    }
    atomicAdd(&g[(size_t)cur * HC + f], pool);
}

// ---------------- K5: tiny 2-layer MLP on pooled graphs ------------------
__global__ __launch_bounds__(64) void k_mlp(const float* __restrict__ g,
                                            const float* __restrict__ w1,
                                            const float* __restrict__ bb1,
                                            const float* __restrict__ w2,
                                            const float* __restrict__ bb2,
                                            float* __restrict__ out) {
    __shared__ float sg[HC];
    __shared__ float st[HID];
    int b = blockIdx.x;
    int t = threadIdx.x;   // 64
    sg[t]      = g[(size_t)b * HC + t];
    sg[t + 64] = g[(size_t)b * HC + 64 + t];
    __syncthreads();
    if (t < HID) {
        float acc = bb1[t];
#pragma unroll 8
        for (int k = 0; k < HC; k++) acc += sg[k] * w1[(size_t)k * HID + t];
        st[t] = acc;
    }
    __syncthreads();
    if (t < OUT_CH) {
        float acc = bb2[t];
#pragma unroll
        for (int k = 0; k < HID; k++) acc += st[k] * w2[(size_t)k * OUT_CH + t];
        out[(size_t)b * OUT_CH + t] = acc;
    }
}

extern "C" void kernel_launch(void* const* d_in, const int* in_sizes, int n_in,
                              void* d_out, int out_size, void* d_ws, size_t ws_size,
                              hipStream_t stream) {
    const float* x       = (const float*)d_in[0];
    const int*   ei      = (const int*)d_in[1];
    const int*   batch   = (const int*)d_in[2];
    const float* W1      = (const float*)d_in[3];
    const float* att_src = (const float*)d_in[4];
    const float* att_dst = (const float*)d_in[5];
    const float* b1      = (const float*)d_in[6];
    const float* lin1_w  = (const float*)d_in[7];
    const float* lin1_b  = (const float*)d_in[8];
    const float* lin2_w  = (const float*)d_in[9];
    const float* lin2_b  = (const float*)d_in[10];
    float* out = (float*)d_out;

    float* ws = (float*)d_ws;
    // layout (float-offsets into ws):
    unsigned short* hb  = (unsigned short*)ws;    // N*128 bf16 -> 3,200,000 floats
    float*  a_s     = ws + 3200000;               //   200,000
    float*  a_d     = ws + 3400000;               //   200,000
    int*    csr_src = (int*)(ws + 3600000);       // N*CAP = 4,800,000
    uint2*  csr_ev  = (uint2*)(ws + 8400000);     // N*CAP uint2 = 9,600,000 floats
    int*    cnt     = (int*)(ws + 18000000);      //    50,000
    float*  g       = ws + 18050000;              //    65,536
    // total ~18.12M floats = 72.5 MB

    hipMemsetAsync(cnt, 0, (size_t)N_NODES * sizeof(int), stream);
    hipMemsetAsync(g, 0, (size_t)B_GRAPHS * HC * sizeof(float), stream);

    k_gemm_h<<<(N_NODES + ROWS_PB - 1) / ROWS_PB, 256, 0, stream>>>(
        x, W1, att_src, att_dst, hb, a_s, a_d);
    k_bucket<<<(EP + 255) / 256, 256, 0, stream>>>(ei, cnt, csr_src);
    k_ev<<<(N_NODES * CAP) / 256, 256, 0, stream>>>(csr_src, cnt, a_s, a_d, csr_ev);
    k_agg_pool<<<N_NODES / AGG_CHUNK, 128, 0, stream>>>(
        cnt, csr_src, csr_ev, hb, b1, batch, g);
    k_mlp<<<B_GRAPHS, 64, 0, stream>>>(g, lin1_w, lin1_b, lin2_w, lin2_b, out);
}

// Round 8
// 337.106 us; speedup vs baseline: 1.0826x; 1.0826x over previous
//
#include <hip/hip_runtime.h>
#include <hip/hip_bf16.h>
#include <hip/hip_fp16.h>

#define N_NODES 50000
#define E_EDGES 1600000
#define EP (E_EDGES + N_NODES)   // edges + self loops = 1650000
#define IN_CH 128
#define HID 32
#define HEADS 4
#define HC (HEADS * HID)         // 128
#define OUT_CH 16
#define B_GRAPHS 512
#define NEG_SLOPE 0.2f
#define CAP 96                   // bucket capacity; deg = 1+Pois(32), P(>96)~1e-18
#define NSLICE 8                 // one dst-slice per XCD (blockIdx%8 round-robin)
#define SLICE_N 6250             // N_NODES / NSLICE
#define BUCKET_GRPS 256          // blocks per slice

__device__ __forceinline__ unsigned short f2bf(float f) {
    unsigned int u = __float_as_uint(f);
    unsigned int r = (u + 0x7FFFu + ((u >> 16) & 1u)) >> 16;   // RNE
    return (unsigned short)r;
}

__device__ __forceinline__ float lrelu_exp(float v) {
    v = v > 0.f ? v : NEG_SLOPE * v;
    return __expf(v);
}

// ---- K1: XCD-sliced bucket fill ----------------------------------------
// slice = blockIdx%8 -> XCD round-robin; each slice-group scans all edges,
// processes only dst in its slice. Writes stay in one XCD's L2 slice region
// (2.4 MB < 4 MB L2) so lines fill before eviction.
__global__ __launch_bounds__(256) void k_bucket(const int* __restrict__ ei,
                                                int* __restrict__ cnt,
                                                int* __restrict__ csr_src) {
    const int t = threadIdx.x;
    const int slice = blockIdx.x & (NSLICE - 1);
    const int grp = blockIdx.x >> 3;        // 0..BUCKET_GRPS-1
    const int lo = slice * SLICE_N;
    const int hi = lo + SLICE_N;
    for (int e = grp * 256 + t; e < EP; e += BUCKET_GRPS * 256) {
        int d = (e < E_EDGES) ? ei[E_EDGES + e] : (e - E_EDGES);
        if (d >= lo && d < hi) {
            int s = (e < E_EDGES) ? ei[e] : d;
            int c = atomicAdd(&cnt[d], 1);
            if (c < CAP) csr_src[d * CAP + c] = s;
        }
    }
}

// ---- K2: GEMM h = x@W1 (8x4 reg tile, k-vec4) + bf16 h + attn + g-zero --
#define ROWS_PB 64
__global__ __launch_bounds__(256) void k_gemm_h(const float* __restrict__ x,
                                                const float* __restrict__ W1,
                                                const float* __restrict__ att_src,
                                                const float* __restrict__ att_dst,
                                                unsigned short* __restrict__ hb,
                                                float* __restrict__ a_s,
                                                float* __restrict__ a_d,
                                                float* __restrict__ g) {
    __shared__ float smem[12288];          // 48 KB: sX 8192 | sW 4096
    float* sX = smem;                      // [64][128]
    float* sW = smem + 8192;               // [32][128]
    const int t = threadIdx.x;
    const int n0 = blockIdx.x * ROWS_PB;

    // fused: zero pooled-graph accumulator for k_agg_pool
    int gt = blockIdx.x * 256 + t;
    if (gt < B_GRAPHS * HC) g[gt] = 0.f;

    // stage x tile (float4)
    for (int i = t; i < ROWS_PB * 32; i += 256) {
        int r = i >> 5, c4 = i & 31;
        int n = n0 + r;
        float4 v = (n < N_NODES) ? ((const float4*)x)[(size_t)n * 32 + c4]
                                 : make_float4(0.f, 0.f, 0.f, 0.f);
        ((float4*)sX)[i] = v;
    }

    float acc[8][4];
#pragma unroll
    for (int j = 0; j < 8; j++)
#pragma unroll
        for (int c = 0; c < 4; c++) acc[j][c] = 0.f;

    const int tx = t & 31;    // col group: cols 4tx..4tx+3
    const int ty = t >> 5;    // row group: rows 8ty..8ty+7

    for (int kb = 0; kb < 4; kb++) {
        __syncthreads();
        for (int i = t; i < 32 * 32; i += 256) {
            ((float4*)sW)[i] =
                ((const float4*)W1)[(size_t)(kb * 32 + (i >> 5)) * 32 + (i & 31)];
        }
        __syncthreads();
#pragma unroll
        for (int kk = 0; kk < 32; kk += 4) {
            float4 w0 = *(float4*)&sW[(kk + 0) * 128 + tx * 4];
            float4 w1 = *(float4*)&sW[(kk + 1) * 128 + tx * 4];
            float4 w2 = *(float4*)&sW[(kk + 2) * 128 + tx * 4];
            float4 w3 = *(float4*)&sW[(kk + 3) * 128 + tx * 4];
#pragma unroll
            for (int j = 0; j < 8; j++) {
                float4 xv = *(float4*)&sX[(ty * 8 + j) * 128 + kb * 32 + kk];
                acc[j][0] += xv.x * w0.x + xv.y * w1.x + xv.z * w2.x + xv.w * w3.x;
                acc[j][1] += xv.x * w0.y + xv.y * w1.y + xv.z * w2.y + xv.w * w3.y;
                acc[j][2] += xv.x * w0.z + xv.y * w1.z + xv.z * w2.z + xv.w * w3.z;
                acc[j][3] += xv.x * w0.w + xv.y * w1.w + xv.z * w2.w + xv.w * w3.w;
            }
        }
    }

    // store h as bf16 (ushort4 = 4 channels)
#pragma unroll
    for (int j = 0; j < 8; j++) {
        int n = n0 + ty * 8 + j;
        if (n < N_NODES) {
            ushort4 o;
            o.x = f2bf(acc[j][0]); o.y = f2bf(acc[j][1]);
            o.z = f2bf(acc[j][2]); o.w = f2bf(acc[j][3]);
            *(ushort4*)&hb[(size_t)n * HC + tx * 4] = o;
        }
    }

    // attention scores from the fp32 tile (restash with pad-129)
    __syncthreads();
    float* sH = smem;                      // [64][129] = 33 KB
#pragma unroll
    for (int j = 0; j < 8; j++) {
        float* row = &sH[(ty * 8 + j) * 129 + tx * 4];
        row[0] = acc[j][0]; row[1] = acc[j][1];
        row[2] = acc[j][2]; row[3] = acc[j][3];
    }
    __syncthreads();
    if (t < 128) {
        int r = t & 63;
        int n = n0 + r;
        const float* __restrict__ av = (t < 64) ? att_src : att_dst;
        float s0 = 0.f, s1 = 0.f, s2 = 0.f, s3 = 0.f;
#pragma unroll 4
        for (int j = 0; j < 32; j++) {
            const float* row = &sH[r * 129 + j];
            s0 += row[0]  * av[j];
            s1 += row[32] * av[32 + j];
            s2 += row[64] * av[64 + j];
            s3 += row[96] * av[96 + j];
        }
        if (n < N_NODES) {
            float* dst = (t < 64) ? a_s : a_d;
            *(float4*)(dst + (size_t)n * 4) = make_float4(s0, s1, s2, s3);
        }
    }
}

// ---- K3: aggregate with fused edge-weight compute (LDS) + ELU + pool ----
// Per node: phase A (96 threads) computes exp weights -> LDS (stride 97),
// phase B (128 channel threads) does the weighted gather of bf16 h.
#define AGG_CHUNK 8
__global__ __launch_bounds__(128) void k_agg_pool(const int* __restrict__ cnt,
                                                  const int* __restrict__ csr_src,
                                                  const float* __restrict__ a_s,
                                                  const float* __restrict__ a_d,
                                                  const unsigned short* __restrict__ hb,
                                                  const float* __restrict__ b1,
                                                  const int* __restrict__ batch,
                                                  float* __restrict__ g) {
    __shared__ int   s_src[CAP];
    __shared__ float s_w[4 * 97];          // stride 97: heads hit distinct banks
    const int f = threadIdx.x;             // 0..127 feature channel
    const int head = f >> 5;               // 0..3
    const int n0 = blockIdx.x * AGG_CHUNK;
    const float bias = b1[f];
    float pool = 0.f;
    int cur = batch[n0];
    for (int n = n0; n < n0 + AGG_CHUNK; n++) {
        int b = batch[n];
        if (b != cur) {                    // uniform branch
            atomicAdd(&g[(size_t)cur * HC + f], pool);
            pool = 0.f;
            cur = b;
        }
        int c = cnt[n]; if (c > CAP) c = CAP;
        __syncthreads();                   // LDS reuse from previous node
        if (f < c) {
            int s = csr_src[n * CAP + f];
            s_src[f] = s;
            float4 as = *(const float4*)(a_s + (size_t)s * 4);
            float4 ad = *(const float4*)(a_d + (size_t)n * 4);
            s_w[0 * 97 + f] = lrelu_exp(as.x + ad.x);
            s_w[1 * 97 + f] = lrelu_exp(as.y + ad.y);
            s_w[2 * 97 + f] = lrelu_exp(as.z + ad.z);
            s_w[3 * 97 + f] = lrelu_exp(as.w + ad.w);
        }
        __syncthreads();
        float acc = 0.f, dsum = 0.f;
        int i = 0;
        for (; i + 2 <= c; i += 2) {       // 2-edge interleave for MLP
            int s0 = s_src[i];
            int s1 = s_src[i + 1];
            float w0 = s_w[head * 97 + i];
            float w1 = s_w[head * 97 + i + 1];
            unsigned short u0 = hb[(size_t)s0 * HC + f];   // coalesced 256B
            unsigned short u1 = hb[(size_t)s1 * HC + f];
            dsum += w0 + w1;
            acc += w0 * __uint_as_float((unsigned int)u0 << 16)
                 + w1 * __uint_as_float((unsigned int)u1 << 16);
        }
        if (i < c) {
            int s0 = s_src[i];
            float w0 = s_w[head * 97 + i];
            unsigned short u0 = hb[(size_t)s0 * HC + f];
            dsum += w0;
            acc += w0 * __uint_as_float((unsigned int)u0 << 16);
        }
        float inv = 1.f / (dsum + 1e-16f);
        float val = acc * inv + bias;
        val = val > 0.f ? val : (__expf(val) - 1.f);       // ELU
        pool += val;
    }
    atomicAdd(&g[(size_t)cur * HC + f], pool);
}

// ---------------- K4: tiny 2-layer MLP on pooled graphs ------------------
__global__ __launch_bounds__(64) void k_mlp(const float* __restrict__ g,
                                            const float* __restrict__ w1,
                                            const float* __restrict__ bb1,
                                            const float* __restrict__ w2,
                                            const float* __restrict__ bb2,
                                            float* __restrict__ out) {
    __shared__ float sg[HC];
    __shared__ float st[HID];
    int b = blockIdx.x;
    int t = threadIdx.x;   // 64
    sg[t]      = g[(size_t)b * HC + t];
    sg[t + 64] = g[(size_t)b * HC + 64 + t];
    __syncthreads();
    if (t < HID) {
        float acc = bb1[t];
#pragma unroll 8
        for (int k = 0; k < HC; k++) acc += sg[k] * w1[(size_t)k * HID + t];
        st[t] = acc;
    }
    __syncthreads();
    if (t < OUT_CH) {
        float acc = bb2[t];
#pragma unroll
        for (int k = 0; k < HID; k++) acc += st[k] * w2[(size_t)k * OUT_CH + t];
        out[(size_t)b * OUT_CH + t] = acc;
    }
}

extern "C" void kernel_launch(void* const* d_in, const int* in_sizes, int n_in,
                              void* d_out, int out_size, void* d_ws, size_t ws_size,
                              hipStream_t stream) {
    const float* x       = (const float*)d_in[0];
    const int*   ei      = (const int*)d_in[1];
    const int*   batch   = (const int*)d_in[2];
    const float* W1      = (const float*)d_in[3];
    const float* att_src = (const float*)d_in[4];
    const float* att_dst = (const float*)d_in[5];
    const float* b1      = (const float*)d_in[6];
    const float* lin1_w  = (const float*)d_in[7];
    const float* lin1_b  = (const float*)d_in[8];
    const float* lin2_w  = (const float*)d_in[9];
    const float* lin2_b  = (const float*)d_in[10];
    float* out = (float*)d_out;

    float* ws = (float*)d_ws;
    // layout (float-offsets into ws):
    unsigned short* hb  = (unsigned short*)ws;    // N*128 bf16 -> 3,200,000 floats
    float*  a_s     = ws + 3200000;               //   200,000
    float*  a_d     = ws + 3400000;               //   200,000
    int*    csr_src = (int*)(ws + 3600000);       // N*CAP = 4,800,000
    int*    cnt     = (int*)(ws + 8400000);       //    50,000
    float*  g       = ws + 8450000;               //    65,536
    // total ~8.52M floats = 34 MB

    hipMemsetAsync(cnt, 0, (size_t)N_NODES * sizeof(int), stream);

    k_bucket<<<NSLICE * BUCKET_GRPS, 256, 0, stream>>>(ei, cnt, csr_src);
    k_gemm_h<<<(N_NODES + ROWS_PB - 1) / ROWS_PB, 256, 0, stream>>>(
        x, W1, att_src, att_dst, hb, a_s, a_d, g);
    k_agg_pool<<<N_NODES / AGG_CHUNK, 128, 0, stream>>>(
        cnt, csr_src, a_s, a_d, hb, b1, batch, g);
    k_mlp<<<B_GRAPHS, 64, 0, stream>>>(g, lin1_w, lin1_b, lin2_w, lin2_b, out);
}

// Round 9
// 276.559 us; speedup vs baseline: 1.3196x; 1.2189x over previous
//
#include <hip/hip_runtime.h>
#include <hip/hip_bf16.h>
#include <hip/hip_fp16.h>

#define N_NODES 50000
#define E_EDGES 1600000
#define EP (E_EDGES + N_NODES)   // edges + self loops = 1650000
#define IN_CH 128
#define HID 32
#define HEADS 4
#define HC (HEADS * HID)         // 128
#define OUT_CH 16
#define B_GRAPHS 512
#define NEG_SLOPE 0.2f
#define CAP 96                   // bucket capacity; deg = 1+Pois(32), P(>96)~1e-18
#define NSLICE 8                 // dst-slice per XCD (blockIdx%8 round-robin)
#define SLICE_N 6250             // N_NODES / NSLICE
#define BUCKET_GRPS 128          // blocks per slice
#define BUCKET_BLOCKS (NSLICE * BUCKET_GRPS)   // 1024
#define GEMM_BLOCKS 782          // ceil(50000/64)

__device__ __forceinline__ unsigned short f2bf(float f) {
    unsigned int u = __float_as_uint(f);
    unsigned int r = (u + 0x7FFFu + ((u >> 16) & 1u)) >> 16;   // RNE
    return (unsigned short)r;
}

__device__ __forceinline__ float lrelu_exp(float v) {
    v = v > 0.f ? v : NEG_SLOPE * v;
    return __expf(v);
}

// ---- K1: fused XCD-sliced bucket fill + GEMM + bf16 h + attn + g-zero ---
#define ROWS_PB 64
__global__ __launch_bounds__(256) void k_fused(const float* __restrict__ x,
                                               const float* __restrict__ W1,
                                               const float* __restrict__ att_src,
                                               const float* __restrict__ att_dst,
                                               const int* __restrict__ ei,
                                               unsigned short* __restrict__ hb,
                                               float* __restrict__ a_s,
                                               float* __restrict__ a_d,
                                               int* __restrict__ cnt,
                                               int* __restrict__ csr_src,
                                               float* __restrict__ g) {
    __shared__ float smem[12288];          // 48 KB: sX 8192 | sW 4096
    const int t = threadIdx.x;

    if (blockIdx.x < BUCKET_BLOCKS) {
        // ---- bucket fill, slice = blockIdx%8 (XCD round-robin) ----
        const int slice = blockIdx.x & (NSLICE - 1);
        const int grp = blockIdx.x >> 3;            // 0..BUCKET_GRPS-1
        const int lo = slice * SLICE_N;
        const int hi = lo + SLICE_N;
        const int* __restrict__ dstp = ei + E_EDGES;
        // self loops of my slice (branchless membership)
        for (int i = grp * 256 + t; i < SLICE_N; i += BUCKET_GRPS * 256) {
            int d = lo + i;
            int c = atomicAdd(&cnt[d], 1);
            if (c < CAP) csr_src[d * CAP + c] = d;
        }
        // real edges, int4-vectorized dst scan
        for (int idx = grp * 256 + t; idx < E_EDGES / 4; idx += BUCKET_GRPS * 256) {
            int4 d4 = ((const int4*)dstp)[idx];
            int e0 = idx * 4;
            if (d4.x >= lo && d4.x < hi) {
                int c = atomicAdd(&cnt[d4.x], 1);
                if (c < CAP) csr_src[d4.x * CAP + c] = ei[e0];
            }
            if (d4.y >= lo && d4.y < hi) {
                int c = atomicAdd(&cnt[d4.y], 1);
                if (c < CAP) csr_src[d4.y * CAP + c] = ei[e0 + 1];
            }
            if (d4.z >= lo && d4.z < hi) {
                int c = atomicAdd(&cnt[d4.z], 1);
                if (c < CAP) csr_src[d4.z * CAP + c] = ei[e0 + 2];
            }
            if (d4.w >= lo && d4.w < hi) {
                int c = atomicAdd(&cnt[d4.w], 1);
                if (c < CAP) csr_src[d4.w * CAP + c] = ei[e0 + 3];
            }
        }
        return;                            // uniform exit, no barrier crossed
    }

    // ---- GEMM part ----
    float* sX = smem;                      // [64][128]
    float* sW = smem + 8192;               // [32][128]
    const int bid = blockIdx.x - BUCKET_BLOCKS;
    const int n0 = bid * ROWS_PB;

    // fused: zero pooled-graph accumulator
    int gt = bid * 256 + t;
    if (gt < B_GRAPHS * HC) g[gt] = 0.f;

    for (int i = t; i < ROWS_PB * 32; i += 256) {
        int r = i >> 5, c4 = i & 31;
        int n = n0 + r;
        float4 v = (n < N_NODES) ? ((const float4*)x)[(size_t)n * 32 + c4]
                                 : make_float4(0.f, 0.f, 0.f, 0.f);
        ((float4*)sX)[i] = v;
    }

    float acc[8][4];
#pragma unroll
    for (int j = 0; j < 8; j++)
#pragma unroll
        for (int c = 0; c < 4; c++) acc[j][c] = 0.f;

    const int tx = t & 31;    // col group: cols 4tx..4tx+3
    const int ty = t >> 5;    // row group: rows 8ty..8ty+7

    for (int kb = 0; kb < 4; kb++) {
        __syncthreads();
        for (int i = t; i < 32 * 32; i += 256) {
            ((float4*)sW)[i] =
                ((const float4*)W1)[(size_t)(kb * 32 + (i >> 5)) * 32 + (i & 31)];
        }
        __syncthreads();
#pragma unroll
        for (int kk = 0; kk < 32; kk += 4) {
            float4 w0 = *(float4*)&sW[(kk + 0) * 128 + tx * 4];
            float4 w1 = *(float4*)&sW[(kk + 1) * 128 + tx * 4];
            float4 w2 = *(float4*)&sW[(kk + 2) * 128 + tx * 4];
            float4 w3 = *(float4*)&sW[(kk + 3) * 128 + tx * 4];
#pragma unroll
            for (int j = 0; j < 8; j++) {
                float4 xv = *(float4*)&sX[(ty * 8 + j) * 128 + kb * 32 + kk];
                acc[j][0] += xv.x * w0.x + xv.y * w1.x + xv.z * w2.x + xv.w * w3.x;
                acc[j][1] += xv.x * w0.y + xv.y * w1.y + xv.z * w2.y + xv.w * w3.y;
                acc[j][2] += xv.x * w0.z + xv.y * w1.z + xv.z * w2.z + xv.w * w3.z;
                acc[j][3] += xv.x * w0.w + xv.y * w1.w + xv.z * w2.w + xv.w * w3.w;
            }
        }
    }

#pragma unroll
    for (int j = 0; j < 8; j++) {
        int n = n0 + ty * 8 + j;
        if (n < N_NODES) {
            ushort4 o;
            o.x = f2bf(acc[j][0]); o.y = f2bf(acc[j][1]);
            o.z = f2bf(acc[j][2]); o.w = f2bf(acc[j][3]);
            *(ushort4*)&hb[(size_t)n * HC + tx * 4] = o;
        }
    }

    // attention scores from the fp32 tile (restash with pad-129)
    __syncthreads();
    float* sH = smem;                      // [64][129] = 33 KB
#pragma unroll
    for (int j = 0; j < 8; j++) {
        float* row = &sH[(ty * 8 + j) * 129 + tx * 4];
        row[0] = acc[j][0]; row[1] = acc[j][1];
        row[2] = acc[j][2]; row[3] = acc[j][3];
    }
    __syncthreads();
    if (t < 128) {
        int r = t & 63;
        int n = n0 + r;
        const float* __restrict__ av = (t < 64) ? att_src : att_dst;
        float s0 = 0.f, s1 = 0.f, s2 = 0.f, s3 = 0.f;
#pragma unroll 4
        for (int j = 0; j < 32; j++) {
            const float* row = &sH[r * 129 + j];
            s0 += row[0]  * av[j];
            s1 += row[32] * av[32 + j];
            s2 += row[64] * av[64 + j];
            s3 += row[96] * av[96 + j];
        }
        if (n < N_NODES) {
            float* dst = (t < 64) ? a_s : a_d;
            *(float4*)(dst + (size_t)n * 4) = make_float4(s0, s1, s2, s3);
        }
    }
}

// ---- K2: wave-per-node aggregate: 2 ch/lane, per-wave LDS weights -------
// No __syncthreads: LDS ops are in-order within a wave; clobber stops
// compiler reordering only.
#define ANW 4                     // nodes per wave; block = 2 waves = 8 nodes
__global__ __launch_bounds__(128) void k_agg_pool(const int* __restrict__ cnt,
                                                  const int* __restrict__ csr_src,
                                                  const float* __restrict__ a_s,
                                                  const float* __restrict__ a_d,
                                                  const unsigned short* __restrict__ hb,
                                                  const float* __restrict__ b1,
                                                  const int* __restrict__ batch,
                                                  float* __restrict__ g) {
    __shared__ int   sS[2][CAP];
    __shared__ float sWt[2][4][100];       // stride 100: heads 4 banks apart
    const int t = threadIdx.x;
    const int wv = t >> 6;                 // wave in block
    const int l = t & 63;                  // lane
    const int head = l >> 4;               // head of my 2 channels
    const int c0 = 2 * l;                  // channels c0, c0+1
    const int n0 = blockIdx.x * (2 * ANW) + wv * ANW;
    const float2 bias = *(const float2*)(b1 + c0);
    float pool0 = 0.f, pool1 = 0.f;
    int cur = batch[n0];
    for (int n = n0; n < n0 + ANW; n++) {
        int b = batch[n];
        if (b != cur) {                    // wave-uniform branch
            atomicAdd(&g[(size_t)cur * HC + c0], pool0);
            atomicAdd(&g[(size_t)cur * HC + c0 + 1], pool1);
            pool0 = pool1 = 0.f;
            cur = b;
        }
        int c = cnt[n]; if (c > CAP) c = CAP;
        float4 ad = *(const float4*)(a_d + (size_t)n * 4);
        for (int i = l; i < c; i += 64) {  // fill phase (this wave only)
            int s = csr_src[n * CAP + i];
            sS[wv][i] = s;
            float4 as = *(const float4*)(a_s + (size_t)s * 4);
            sWt[wv][0][i] = lrelu_exp(as.x + ad.x);
            sWt[wv][1][i] = lrelu_exp(as.y + ad.y);
            sWt[wv][2][i] = lrelu_exp(as.z + ad.z);
            sWt[wv][3][i] = lrelu_exp(as.w + ad.w);
        }
        __asm__ volatile("" ::: "memory"); // compiler barrier (wave-coherent LDS)
        const float* __restrict__ wrow = &sWt[wv][head][0];
        const int* __restrict__ srow = &sS[wv][0];
        float acc0 = 0.f, acc1 = 0.f, dsum = 0.f;
        int i = 0;
        for (; i + 4 <= c; i += 4) {       // 4-edge interleave for MLP
            int s0 = srow[i], s1 = srow[i + 1], s2 = srow[i + 2], s3 = srow[i + 3];
            float w0 = wrow[i], w1 = wrow[i + 1], w2 = wrow[i + 2], w3 = wrow[i + 3];
            unsigned int u0 = *(const unsigned int*)(hb + (size_t)s0 * HC + c0);
            unsigned int u1 = *(const unsigned int*)(hb + (size_t)s1 * HC + c0);
            unsigned int u2 = *(const unsigned int*)(hb + (size_t)s2 * HC + c0);
            unsigned int u3 = *(const unsigned int*)(hb + (size_t)s3 * HC + c0);
            dsum += (w0 + w1) + (w2 + w3);
            acc0 += w0 * __uint_as_float(u0 << 16) + w1 * __uint_as_float(u1 << 16)
                  + w2 * __uint_as_float(u2 << 16) + w3 * __uint_as_float(u3 << 16);
            acc1 += w0 * __uint_as_float(u0 & 0xFFFF0000u)
                  + w1 * __uint_as_float(u1 & 0xFFFF0000u)
                  + w2 * __uint_as_float(u2 & 0xFFFF0000u)
                  + w3 * __uint_as_float(u3 & 0xFFFF0000u);
        }
        for (; i < c; i++) {
            int s0 = srow[i];
            float w0 = wrow[i];
            unsigned int u0 = *(const unsigned int*)(hb + (size_t)s0 * HC + c0);
            dsum += w0;
            acc0 += w0 * __uint_as_float(u0 << 16);
            acc1 += w0 * __uint_as_float(u0 & 0xFFFF0000u);
        }
        __asm__ volatile("" ::: "memory");
        float inv = 1.f / (dsum + 1e-16f);
        float v0 = acc0 * inv + bias.x; v0 = v0 > 0.f ? v0 : (__expf(v0) - 1.f);
        float v1 = acc1 * inv + bias.y; v1 = v1 > 0.f ? v1 : (__expf(v1) - 1.f);
        pool0 += v0;
        pool1 += v1;
    }
    atomicAdd(&g[(size_t)cur * HC + c0], pool0);
    atomicAdd(&g[(size_t)cur * HC + c0 + 1], pool1);
}

// ---------------- K3: tiny 2-layer MLP on pooled graphs ------------------
__global__ __launch_bounds__(64) void k_mlp(const float* __restrict__ g,
                                            const float* __restrict__ w1,
                                            const float* __restrict__ bb1,
                                            const float* __restrict__ w2,
                                            const float* __restrict__ bb2,
                                            float* __restrict__ out) {
    __shared__ float sg[HC];
    __shared__ float st[HID];
    int b = blockIdx.x;
    int t = threadIdx.x;   // 64
    sg[t]      = g[(size_t)b * HC + t];
    sg[t + 64] = g[(size_t)b * HC + 64 + t];
    __syncthreads();
    if (t < HID) {
        float acc = bb1[t];
#pragma unroll 8
        for (int k = 0; k < HC; k++) acc += sg[k] * w1[(size_t)k * HID + t];
        st[t] = acc;
    }
    __syncthreads();
    if (t < OUT_CH) {
        float acc = bb2[t];
#pragma unroll
        for (int k = 0; k < HID; k++) acc += st[k] * w2[(size_t)k * OUT_CH + t];
        out[(size_t)b * OUT_CH + t] = acc;
    }
}

extern "C" void kernel_launch(void* const* d_in, const int* in_sizes, int n_in,
                              void* d_out, int out_size, void* d_ws, size_t ws_size,
                              hipStream_t stream) {
    const float* x       = (const float*)d_in[0];
    const int*   ei      = (const int*)d_in[1];
    const int*   batch   = (const int*)d_in[2];
    const float* W1      = (const float*)d_in[3];
    const float* att_src = (const float*)d_in[4];
    const float* att_dst = (const float*)d_in[5];
    const float* b1      = (const float*)d_in[6];
    const float* lin1_w  = (const float*)d_in[7];
    const float* lin1_b  = (const float*)d_in[8];
    const float* lin2_w  = (const float*)d_in[9];
    const float* lin2_b  = (const float*)d_in[10];
    float* out = (float*)d_out;

    float* ws = (float*)d_ws;
    // layout (float-offsets into ws):
    unsigned short* hb  = (unsigned short*)ws;    // N*128 bf16 -> 3,200,000 floats
    float*  a_s     = ws + 3200000;               //   200,000
    float*  a_d     = ws + 3400000;               //   200,000
    int*    csr_src = (int*)(ws + 3600000);       // N*CAP = 4,800,000
    int*    cnt     = (int*)(ws + 8400000);       //    50,000
    float*  g       = ws + 8450000;               //    65,536
    // total ~8.52M floats = 34 MB

    hipMemsetAsync(cnt, 0, (size_t)N_NODES * sizeof(int), stream);

    k_fused<<<BUCKET_BLOCKS + GEMM_BLOCKS, 256, 0, stream>>>(
        x, W1, att_src, att_dst, ei, hb, a_s, a_d, cnt, csr_src, g);
    k_agg_pool<<<N_NODES / (2 * ANW), 128, 0, stream>>>(
        cnt, csr_src, a_s, a_d, hb, b1, batch, g);
    k_mlp<<<B_GRAPHS, 64, 0, stream>>>(g, lin1_w, lin1_b, lin2_w, lin2_b, out);
}

// Round 10
// 241.922 us; speedup vs baseline: 1.5085x; 1.1432x over previous
//
#include <hip/hip_runtime.h>
#include <hip/hip_bf16.h>
#include <hip/hip_fp16.h>

#define N_NODES 50000
#define E_EDGES 1600000
#define EP (E_EDGES + N_NODES)
#define IN_CH 128
#define HID 32
#define HEADS 4
#define HC (HEADS * HID)         // 128
#define OUT_CH 16
#define B_GRAPHS 512
#define NEG_SLOPE 0.2f
#define CAP 96                   // per-node capacity; deg = 1+Pois(32), P(>96)~1e-18
#define NB 256                   // coarse buckets
#define BNODES 196               // nodes per bucket (256*196 = 50176 >= 50000)
#define PCAP 7168                // per-bucket edge capacity (mean 6250, sd 79; +11.6 sd)
#define ACHUNK 4096              // edges per pass-A block

__device__ __forceinline__ unsigned short f2bf(float f) {
    unsigned int u = __float_as_uint(f);
    unsigned int r = (u + 0x7FFFu + ((u >> 16) & 1u)) >> 16;   // RNE
    return (unsigned short)r;
}

__device__ __forceinline__ float lrelu_exp(float v) {
    v = v > 0.f ? v : NEG_SLOPE * v;
    return __expf(v);
}

// ---- K1: pass A — coarse partition of edges into 256 dst-buckets --------
// packed entry: (dlocal<<16) | src   (src<65536, dlocal<256)
__global__ __launch_bounds__(256) void k_partA(const int* __restrict__ ei,
                                               int* __restrict__ gcur,
                                               unsigned int* __restrict__ ebuf) {
    __shared__ int scnt[NB];
    __shared__ int sbase[NB];
    const int t = threadIdx.x;
    const int e0 = blockIdx.x * ACHUNK;
    int e1 = e0 + ACHUNK; if (e1 > E_EDGES) e1 = E_EDGES;
    for (int i = t; i < NB; i += 256) scnt[i] = 0;
    __syncthreads();
    const int* __restrict__ dstp = ei + E_EDGES;
    for (int e = e0 + t; e < e1; e += 256) {
        int d = dstp[e];
        atomicAdd(&scnt[d / BNODES], 1);
    }
    __syncthreads();
    for (int b = t; b < NB; b += 256) {
        sbase[b] = atomicAdd(&gcur[b], scnt[b]);
        scnt[b] = 0;
    }
    __syncthreads();
    for (int e = e0 + t; e < e1; e += 256) {
        int d = dstp[e];
        int s = ei[e];
        int b = d / BNODES;
        int dl = d - b * BNODES;
        int pos = sbase[b] + atomicAdd(&scnt[b], 1);
        if (pos < PCAP)
            ebuf[(size_t)b * PCAP + pos] = ((unsigned int)dl << 16) | (unsigned int)s;
    }
}

// ---- K2: pass B — per-bucket CSR build in LDS, coalesced flush ----------
__global__ __launch_bounds__(256) void k_partB(const unsigned int* __restrict__ ebuf,
                                               const int* __restrict__ gcur,
                                               unsigned short* __restrict__ csr,
                                               int* __restrict__ cnt) {
    __shared__ unsigned short sbuf[BNODES * CAP];   // 37632 B
    __shared__ int scnt[BNODES];
    const int t = threadIdx.x;
    const int b = blockIdx.x;
    const int dbase = b * BNODES;
    for (int i = t; i < BNODES; i += 256) {
        int d = dbase + i;
        scnt[i] = (d < N_NODES) ? 1 : 0;            // self loop pre-seeded
        sbuf[i * CAP] = (unsigned short)d;
    }
    __syncthreads();
    int m = gcur[b]; if (m > PCAP) m = PCAP;
    for (int i = t; i < m; i += 256) {
        unsigned int p = ebuf[(size_t)b * PCAP + i];
        int dl = p >> 16;
        int s = p & 0xFFFFu;
        int c = atomicAdd(&scnt[dl], 1);
        if (c < CAP) sbuf[dl * CAP + c] = (unsigned short)s;
    }
    __syncthreads();
    const uint4* sb4 = (const uint4*)sbuf;
    uint4* g4 = (uint4*)(csr + (size_t)dbase * CAP);
    for (int i = t; i < (BNODES * CAP * 2) / 16; i += 256) g4[i] = sb4[i];
    for (int i = t; i < BNODES; i += 256) cnt[dbase + i] = scnt[i];
}

// ---- K3: GEMM h = x@W1 (8x4 reg tile, k-vec4) + bf16 h + attn + g-zero --
#define ROWS_PB 64
__global__ __launch_bounds__(256) void k_gemm_h(const float* __restrict__ x,
                                                const float* __restrict__ W1,
                                                const float* __restrict__ att_src,
                                                const float* __restrict__ att_dst,
                                                unsigned short* __restrict__ hb,
                                                float* __restrict__ a_s,
                                                float* __restrict__ a_d,
                                                float* __restrict__ g) {
    __shared__ float smem[12288];
    float* sX = smem;                      // [64][128]
    float* sW = smem + 8192;               // [32][128]
    const int t = threadIdx.x;
    const int n0 = blockIdx.x * ROWS_PB;

    int gt = blockIdx.x * 256 + t;
    if (gt < B_GRAPHS * HC) g[gt] = 0.f;

    for (int i = t; i < ROWS_PB * 32; i += 256) {
        int r = i >> 5, c4 = i & 31;
        int n = n0 + r;
        float4 v = (n < N_NODES) ? ((const float4*)x)[(size_t)n * 32 + c4]
                                 : make_float4(0.f, 0.f, 0.f, 0.f);
        ((float4*)sX)[i] = v;
    }

    float acc[8][4];
#pragma unroll
    for (int j = 0; j < 8; j++)
#pragma unroll
        for (int c = 0; c < 4; c++) acc[j][c] = 0.f;

    const int tx = t & 31;
    const int ty = t >> 5;

    for (int kb = 0; kb < 4; kb++) {
        __syncthreads();
        for (int i = t; i < 32 * 32; i += 256) {
            ((float4*)sW)[i] =
                ((const float4*)W1)[(size_t)(kb * 32 + (i >> 5)) * 32 + (i & 31)];
        }
        __syncthreads();
#pragma unroll
        for (int kk = 0; kk < 32; kk += 4) {
            float4 w0 = *(float4*)&sW[(kk + 0) * 128 + tx * 4];
            float4 w1 = *(float4*)&sW[(kk + 1) * 128 + tx * 4];
            float4 w2 = *(float4*)&sW[(kk + 2) * 128 + tx * 4];
            float4 w3 = *(float4*)&sW[(kk + 3) * 128 + tx * 4];
#pragma unroll
            for (int j = 0; j < 8; j++) {
                float4 xv = *(float4*)&sX[(ty * 8 + j) * 128 + kb * 32 + kk];
                acc[j][0] += xv.x * w0.x + xv.y * w1.x + xv.z * w2.x + xv.w * w3.x;
                acc[j][1] += xv.x * w0.y + xv.y * w1.y + xv.z * w2.y + xv.w * w3.y;
                acc[j][2] += xv.x * w0.z + xv.y * w1.z + xv.z * w2.z + xv.w * w3.z;
                acc[j][3] += xv.x * w0.w + xv.y * w1.w + xv.z * w2.w + xv.w * w3.w;
            }
        }
    }

#pragma unroll
    for (int j = 0; j < 8; j++) {
        int n = n0 + ty * 8 + j;
        if (n < N_NODES) {
            ushort4 o;
            o.x = f2bf(acc[j][0]); o.y = f2bf(acc[j][1]);
            o.z = f2bf(acc[j][2]); o.w = f2bf(acc[j][3]);
            *(ushort4*)&hb[(size_t)n * HC + tx * 4] = o;
        }
    }

    __syncthreads();
    float* sH = smem;                      // [64][129]
#pragma unroll
    for (int j = 0; j < 8; j++) {
        float* row = &sH[(ty * 8 + j) * 129 + tx * 4];
        row[0] = acc[j][0]; row[1] = acc[j][1];
        row[2] = acc[j][2]; row[3] = acc[j][3];
    }
    __syncthreads();
    if (t < 128) {
        int r = t & 63;
        int n = n0 + r;
        const float* __restrict__ av = (t < 64) ? att_src : att_dst;
        float s0 = 0.f, s1 = 0.f, s2 = 0.f, s3 = 0.f;
#pragma unroll 4
        for (int j = 0; j < 32; j++) {
            const float* row = &sH[r * 129 + j];
            s0 += row[0]  * av[j];
            s1 += row[32] * av[32 + j];
            s2 += row[64] * av[64 + j];
            s3 += row[96] * av[96 + j];
        }
        if (n < N_NODES) {
            float* dst = (t < 64) ? a_s : a_d;
            *(float4*)(dst + (size_t)n * 4) = make_float4(s0, s1, s2, s3);
        }
    }
}

// ---- K4: wave-per-node aggregate (2 ch/lane, per-wave LDS weights) ------
#define ANW 4                     // nodes per wave; block = 4 waves = 16 nodes
__global__ __launch_bounds__(256) void k_agg_pool(const int* __restrict__ cnt,
                                                  const unsigned short* __restrict__ csr,
                                                  const float* __restrict__ a_s,
                                                  const float* __restrict__ a_d,
                                                  const unsigned short* __restrict__ hb,
                                                  const float* __restrict__ b1,
                                                  const int* __restrict__ batch,
                                                  float* __restrict__ g) {
    __shared__ int   sS[4][CAP];
    __shared__ float sWt[4][4][100];       // stride 100: heads 4 banks apart
    const int t = threadIdx.x;
    const int wv = t >> 6;
    const int l = t & 63;
    const int head = l >> 4;
    const int c0 = 2 * l;
    const int n0 = blockIdx.x * (4 * ANW) + wv * ANW;
    const float2 bias = *(const float2*)(b1 + c0);
    float pool0 = 0.f, pool1 = 0.f;
    int cur = batch[n0];
    for (int n = n0; n < n0 + ANW; n++) {
        int b = batch[n];
        if (b != cur) {                    // wave-uniform branch
            atomicAdd(&g[(size_t)cur * HC + c0], pool0);
            atomicAdd(&g[(size_t)cur * HC + c0 + 1], pool1);
            pool0 = pool1 = 0.f;
            cur = b;
        }
        int c = cnt[n]; if (c > CAP) c = CAP;
        float4 ad = *(const float4*)(a_d + (size_t)n * 4);
        for (int i = l; i < c; i += 64) {
            int s = csr[(size_t)n * CAP + i];
            sS[wv][i] = s;
            float4 as = *(const float4*)(a_s + (size_t)s * 4);
            sWt[wv][0][i] = lrelu_exp(as.x + ad.x);
            sWt[wv][1][i] = lrelu_exp(as.y + ad.y);
            sWt[wv][2][i] = lrelu_exp(as.z + ad.z);
            sWt[wv][3][i] = lrelu_exp(as.w + ad.w);
        }
        __asm__ volatile("" ::: "memory");
        const float* __restrict__ wrow = &sWt[wv][head][0];
        const int* __restrict__ srow = &sS[wv][0];
        float acc0 = 0.f, acc1 = 0.f, dsum = 0.f;
        int i = 0;
        for (; i + 4 <= c; i += 4) {
            int s0 = srow[i], s1 = srow[i + 1], s2 = srow[i + 2], s3 = srow[i + 3];
            float w0 = wrow[i], w1 = wrow[i + 1], w2 = wrow[i + 2], w3 = wrow[i + 3];
            unsigned int u0 = *(const unsigned int*)(hb + (size_t)s0 * HC + c0);
            unsigned int u1 = *(const unsigned int*)(hb + (size_t)s1 * HC + c0);
            unsigned int u2 = *(const unsigned int*)(hb + (size_t)s2 * HC + c0);
            unsigned int u3 = *(const unsigned int*)(hb + (size_t)s3 * HC + c0);
            dsum += (w0 + w1) + (w2 + w3);
            acc0 += w0 * __uint_as_float(u0 << 16) + w1 * __uint_as_float(u1 << 16)
                  + w2 * __uint_as_float(u2 << 16) + w3 * __uint_as_float(u3 << 16);
            acc1 += w0 * __uint_as_float(u0 & 0xFFFF0000u)
                  + w1 * __uint_as_float(u1 & 0xFFFF0000u)
                  + w2 * __uint_as_float(u2 & 0xFFFF0000u)
                  + w3 * __uint_as_float(u3 & 0xFFFF0000u);
        }
        for (; i < c; i++) {
            int s0 = srow[i];
            float w0 = wrow[i];
            unsigned int u0 = *(const unsigned int*)(hb + (size_t)s0 * HC + c0);
            dsum += w0;
            acc0 += w0 * __uint_as_float(u0 << 16);
            acc1 += w0 * __uint_as_float(u0 & 0xFFFF0000u);
        }
        __asm__ volatile("" ::: "memory");
        float inv = 1.f / (dsum + 1e-16f);
        float v0 = acc0 * inv + bias.x; v0 = v0 > 0.f ? v0 : (__expf(v0) - 1.f);
        float v1 = acc1 * inv + bias.y; v1 = v1 > 0.f ? v1 : (__expf(v1) - 1.f);
        pool0 += v0;
        pool1 += v1;
    }
    atomicAdd(&g[(size_t)cur * HC + c0], pool0);
    atomicAdd(&g[(size_t)cur * HC + c0 + 1], pool1);
}

// ---------------- K5: tiny 2-layer MLP on pooled graphs ------------------
__global__ __launch_bounds__(64) void k_mlp(const float* __restrict__ g,
                                            const float* __restrict__ w1,
                                            const float* __restrict__ bb1,
                                            const float* __restrict__ w2,
                                            const float* __restrict__ bb2,
                                            float* __restrict__ out) {
    __shared__ float sg[HC];
    __shared__ float st[HID];
    int b = blockIdx.x;
    int t = threadIdx.x;   // 64
    sg[t]      = g[(size_t)b * HC + t];
    sg[t + 64] = g[(size_t)b * HC + 64 + t];
    __syncthreads();
    if (t < HID) {
        float acc = bb1[t];
#pragma unroll 8
        for (int k = 0; k < HC; k++) acc += sg[k] * w1[(size_t)k * HID + t];
        st[t] = acc;
    }
    __syncthreads();
    if (t < OUT_CH) {
        float acc = bb2[t];
#pragma unroll
        for (int k = 0; k < HID; k++) acc += st[k] * w2[(size_t)k * OUT_CH + t];
        out[(size_t)b * OUT_CH + t] = acc;
    }
}

extern "C" void kernel_launch(void* const* d_in, const int* in_sizes, int n_in,
                              void* d_out, int out_size, void* d_ws, size_t ws_size,
                              hipStream_t stream) {
    const float* x       = (const float*)d_in[0];
    const int*   ei      = (const int*)d_in[1];
    const int*   batch   = (const int*)d_in[2];
    const float* W1      = (const float*)d_in[3];
    const float* att_src = (const float*)d_in[4];
    const float* att_dst = (const float*)d_in[5];
    const float* b1      = (const float*)d_in[6];
    const float* lin1_w  = (const float*)d_in[7];
    const float* lin1_b  = (const float*)d_in[8];
    const float* lin2_w  = (const float*)d_in[9];
    const float* lin2_b  = (const float*)d_in[10];
    float* out = (float*)d_out;

    float* ws = (float*)d_ws;
    // layout (float-offsets into ws):
    unsigned short* hb   = (unsigned short*)ws;    // N*128 bf16 -> 3,200,000 floats
    float*  a_s      = ws + 3200000;               //   200,000
    float*  a_d      = ws + 3400000;               //   200,000
    unsigned short* csr = (unsigned short*)(ws + 3600000);  // 50176*96 ush -> 2,408,448 fl
    unsigned int* ebuf = (unsigned int*)(ws + 6010000);     // NB*PCAP = 1,835,008
    int*    cnt      = (int*)(ws + 7850000);       //    50,176
    int*    gcur     = (int*)(ws + 7901000);       //       256
    float*  g        = ws + 7902000;               //    65,536
    // total ~8.0M floats = 32 MB

    hipMemsetAsync(gcur, 0, NB * sizeof(int), stream);

    k_partA<<<(E_EDGES + ACHUNK - 1) / ACHUNK, 256, 0, stream>>>(ei, gcur, ebuf);
    k_partB<<<NB, 256, 0, stream>>>(ebuf, gcur, csr, cnt);
    k_gemm_h<<<(N_NODES + ROWS_PB - 1) / ROWS_PB, 256, 0, stream>>>(
        x, W1, att_src, att_dst, hb, a_s, a_d, g);
    k_agg_pool<<<N_NODES / (4 * ANW), 256, 0, stream>>>(
        cnt, csr, a_s, a_d, hb, b1, batch, g);
    k_mlp<<<B_GRAPHS, 64, 0, stream>>>(g, lin1_w, lin1_b, lin2_w, lin2_b, out);
}